// Round 1
// baseline (1068.366 us; speedup 1.0000x reference)
//
#include <hip/hip_runtime.h>

#define N_NODES 100000
#define N_EDGES 1600000
#define IN_CH 50

// ---- degree count: cnt[dst] += 1 ----
__global__ void count_kernel(const int* __restrict__ dst, float* __restrict__ cnt) {
    int e = blockIdx.x * blockDim.x + threadIdx.x;
    if (e < N_EDGES) atomicAdd(&cnt[dst[e]], 1.0f);
}

// ---- layer-1 scatter: agg[dst, c] += x[src, c], c in [0,50) ----
__global__ void scatter50_kernel(const float* __restrict__ x, const int* __restrict__ src,
                                 const int* __restrict__ dst, float* __restrict__ agg) {
    long long idx = (long long)blockIdx.x * blockDim.x + threadIdx.x;
    if (idx >= (long long)N_EDGES * IN_CH) return;
    int e = (int)(idx / IN_CH);
    int c = (int)(idx - (long long)e * IN_CH);
    int s = src[e], d = dst[e];
    atomicAdd(&agg[(long long)d * IN_CH + c], x[(long long)s * IN_CH + c]);
}

// ---- layer-2 scatter: agg[dst, c] += h1[src, c], c in [0,64) ----
__global__ void scatter64_kernel(const float* __restrict__ h1, const int* __restrict__ src,
                                 const int* __restrict__ dst, float* __restrict__ agg) {
    long long idx = (long long)blockIdx.x * blockDim.x + threadIdx.x;
    if (idx >= (long long)N_EDGES * 64) return;
    int e = (int)(idx >> 6);
    int c = (int)(idx & 63);
    int s = src[e], d = dst[e];
    atomicAdd(&agg[((long long)d << 6) + c], h1[((long long)s << 6) + c]);
}

// ---- layer 1: h1 = relu(concat(x, agg/cnt) @ W1 + b1), one node per 64-thread block ----
__global__ __launch_bounds__(64) void layer1_kernel(
    const float* __restrict__ x, const float* __restrict__ agg, const float* __restrict__ cnt,
    const float* __restrict__ W1, const float* __restrict__ b1, float* __restrict__ h1) {
    int node = blockIdx.x;
    int j = threadIdx.x;
    __shared__ float feat[2 * IN_CH];
    float c = fmaxf(cnt[node], 1.0f);
    if (j < IN_CH) {
        feat[j]         = x[node * IN_CH + j];
        feat[IN_CH + j] = agg[node * IN_CH + j] / c;
    }
    __syncthreads();
    float acc = b1[j];
    #pragma unroll
    for (int k = 0; k < 2 * IN_CH; ++k)
        acc += feat[k] * W1[k * 64 + j];          // lanes j coalesced across W1 row
    h1[(node << 6) + j] = fmaxf(acc, 0.0f);
}

// ---- layers 2+3 fused: h2 = relu(concat(h1, agg/cnt) @ W2 + b2); out = h2 @ W3 + b3 ----
__global__ __launch_bounds__(64) void layer23_kernel(
    const float* __restrict__ h1, const float* __restrict__ agg, const float* __restrict__ cnt,
    const float* __restrict__ W2, const float* __restrict__ b2,
    const float* __restrict__ W3, const float* __restrict__ b3, float* __restrict__ out) {
    int node = blockIdx.x;
    int j = threadIdx.x;
    __shared__ float feat[128];
    float c = fmaxf(cnt[node], 1.0f);
    feat[j]      = h1[(node << 6) + j];
    feat[64 + j] = agg[(node << 6) + j] / c;
    __syncthreads();
    float v = 0.0f;
    if (j < 32) {
        float acc = b2[j];
        #pragma unroll
        for (int k = 0; k < 128; ++k)
            acc += feat[k] * W2[k * 32 + j];      // lanes j coalesced across W2 row
        v = fmaxf(acc, 0.0f) * W3[j];             // fused layer 3 partial product
    }
    // 64-lane reduce (upper 32 lanes carry 0)
    for (int off = 32; off > 0; off >>= 1) v += __shfl_xor(v, off);
    if (j == 0) out[node] = v + b3[0];
}

extern "C" void kernel_launch(void* const* d_in, const int* in_sizes, int n_in,
                              void* d_out, int out_size, void* d_ws, size_t ws_size,
                              hipStream_t stream) {
    const float* x   = (const float*)d_in[0];
    const int*   ei  = (const int*)d_in[1];
    const int*   src = ei;               // edge_index[0]
    const int*   dst = ei + N_EDGES;     // edge_index[1]
    const float* W1  = (const float*)d_in[2];
    const float* b1  = (const float*)d_in[3];
    const float* W2  = (const float*)d_in[4];
    const float* b2  = (const float*)d_in[5];
    const float* W3  = (const float*)d_in[6];
    const float* b3  = (const float*)d_in[7];
    float* out = (float*)d_out;

    // workspace layout: cnt[N] | h1[N*64] | agg[N*64] (agg reused across layers) ~52 MB
    char* ws = (char*)d_ws;
    size_t off0 = 0;
    size_t off1 = ((size_t)N_NODES * 4 + 255) & ~(size_t)255;
    size_t off2 = off1 + (size_t)N_NODES * 64 * 4;
    float* cnt = (float*)(ws + off0);
    float* h1  = (float*)(ws + off1);
    float* agg = (float*)(ws + off2);

    hipMemsetAsync(cnt, 0, (size_t)N_NODES * sizeof(float), stream);
    hipMemsetAsync(agg, 0, (size_t)N_NODES * 64 * sizeof(float), stream);

    count_kernel<<<(N_EDGES + 255) / 256, 256, 0, stream>>>(dst, cnt);

    long long tot1 = (long long)N_EDGES * IN_CH;   // 80M
    scatter50_kernel<<<(int)((tot1 + 255) / 256), 256, 0, stream>>>(x, src, dst, agg);

    layer1_kernel<<<N_NODES, 64, 0, stream>>>(x, agg, cnt, W1, b1, h1);

    hipMemsetAsync(agg, 0, (size_t)N_NODES * 64 * sizeof(float), stream);

    long long tot2 = (long long)N_EDGES * 64;      // 102.4M
    scatter64_kernel<<<(int)((tot2 + 255) / 256), 256, 0, stream>>>(h1, src, dst, agg);

    layer23_kernel<<<N_NODES, 64, 0, stream>>>(h1, agg, cnt, W2, b2, W3, b3, out);
}

// Round 2
// 633.468 us; speedup vs baseline: 1.6865x; 1.6865x over previous
//
#include <hip/hip_runtime.h>

#define N_NODES 100000
#define N_EDGES 1600000
#define IN_CH 50
#define SCAN_CHUNK 512
#define N_CHUNKS ((N_NODES + SCAN_CHUNK - 1) / SCAN_CHUNK)   // 196

// ---- 1. histogram of dst -> cnt (int) ----
__global__ void hist_kernel(const int* __restrict__ dst, int* __restrict__ cnt) {
    int e = blockIdx.x * blockDim.x + threadIdx.x;
    if (e < N_EDGES) atomicAdd(&cnt[dst[e]], 1);
}

// ---- 2a. per-chunk sums (256 threads, 2 items each) ----
__global__ __launch_bounds__(256) void scan1_kernel(const int* __restrict__ cnt,
                                                    int* __restrict__ chunksum) {
    __shared__ int s[256];
    int tid = threadIdx.x;
    int base = blockIdx.x * SCAN_CHUNK;
    int i0 = base + 2 * tid, i1 = i0 + 1;
    int a = (i0 < N_NODES) ? cnt[i0] : 0;
    int b = (i1 < N_NODES) ? cnt[i1] : 0;
    s[tid] = a + b;
    __syncthreads();
    for (int off = 128; off > 0; off >>= 1) {
        if (tid < off) s[tid] += s[tid + off];
        __syncthreads();
    }
    if (tid == 0) chunksum[blockIdx.x] = s[0];
}

// ---- 2b. exclusive scan of chunk sums (single block) ----
__global__ __launch_bounds__(256) void scan2_kernel(const int* __restrict__ chunksum,
                                                    int* __restrict__ chunkoff) {
    __shared__ int s[256];
    int tid = threadIdx.x;
    int v0 = (tid < N_CHUNKS) ? chunksum[tid] : 0;
    s[tid] = v0;
    __syncthreads();
    for (int off = 1; off < 256; off <<= 1) {
        int t = (tid >= off) ? s[tid - off] : 0;
        __syncthreads();
        s[tid] += t;
        __syncthreads();
    }
    if (tid < N_CHUNKS) chunkoff[tid] = s[tid] - v0;
}

// ---- 2c. per-chunk exclusive scan + offset -> row_start, cursor ----
__global__ __launch_bounds__(256) void scan3_kernel(const int* __restrict__ cnt,
                                                    const int* __restrict__ chunkoff,
                                                    int* __restrict__ row_start,
                                                    int* __restrict__ cursor) {
    __shared__ int s[256];
    int tid = threadIdx.x;
    int base = blockIdx.x * SCAN_CHUNK;
    int i0 = base + 2 * tid, i1 = i0 + 1;
    int a = (i0 < N_NODES) ? cnt[i0] : 0;
    int b = (i1 < N_NODES) ? cnt[i1] : 0;
    int pair = a + b;
    s[tid] = pair;
    __syncthreads();
    for (int off = 1; off < 256; off <<= 1) {
        int t = (tid >= off) ? s[tid - off] : 0;
        __syncthreads();
        s[tid] += t;
        __syncthreads();
    }
    int excl = s[tid] - pair;
    int o = chunkoff[blockIdx.x] + excl;
    if (i0 < N_NODES) { row_start[i0] = o;     cursor[i0] = o; }
    if (i1 < N_NODES) { row_start[i1] = o + a; cursor[i1] = o + a; }
}

// ---- 3. bucket placement: csr_src[pos] = src[e] ----
__global__ void fill_kernel(const int* __restrict__ src, const int* __restrict__ dst,
                            int* __restrict__ cursor, int* __restrict__ csr_src) {
    int e = blockIdx.x * blockDim.x + threadIdx.x;
    if (e < N_EDGES) {
        int pos = atomicAdd(&cursor[dst[e]], 1);
        csr_src[pos] = src[e];
    }
}

// ---- 4. layer 1 fused: gather-mean + concat + GEMM(100x64) + ReLU; 1 wave/node ----
__global__ __launch_bounds__(256) void layer1_fused(
    const float* __restrict__ x, const int* __restrict__ csr_src,
    const int* __restrict__ row_start, const int* __restrict__ cnt,
    const float* __restrict__ W1, const float* __restrict__ b1,
    float* __restrict__ h1) {
    int w    = threadIdx.x >> 6;
    int lane = threadIdx.x & 63;
    int node = blockIdx.x * 4 + w;            // N_NODES % 4 == 0, all waves valid

    int start = row_start[node];
    int deg   = cnt[node];
    float sum = 0.0f;
    for (int c0 = 0; c0 < deg; c0 += 64) {
        int myi = c0 + lane;
        int sv  = (myi < deg) ? csr_src[start + myi] : 0;
        int m   = (deg - c0 < 64) ? (deg - c0) : 64;
        for (int j = 0; j < m; ++j) {
            int s = __shfl(sv, j);
            if (lane < IN_CH) sum += x[s * IN_CH + lane];
        }
    }
    float inv = 1.0f / fmaxf((float)deg, 1.0f);

    __shared__ float feat[4][2 * IN_CH];
    if (lane < IN_CH) {
        feat[w][lane]          = x[node * IN_CH + lane];
        feat[w][IN_CH + lane]  = sum * inv;
    }
    __syncthreads();
    float acc = b1[lane];
    #pragma unroll
    for (int k = 0; k < 2 * IN_CH; ++k)
        acc += feat[w][k] * W1[k * 64 + lane];
    h1[(node << 6) + lane] = fmaxf(acc, 0.0f);
}

// ---- 5. layers 2+3 fused: gather-mean(h1) + concat + GEMM(128x32) + ReLU + dot(W3) ----
__global__ __launch_bounds__(256) void layer23_fused(
    const float* __restrict__ h1, const int* __restrict__ csr_src,
    const int* __restrict__ row_start, const int* __restrict__ cnt,
    const float* __restrict__ W2, const float* __restrict__ b2,
    const float* __restrict__ W3, const float* __restrict__ b3,
    float* __restrict__ out) {
    int w    = threadIdx.x >> 6;
    int lane = threadIdx.x & 63;
    int node = blockIdx.x * 4 + w;

    int start = row_start[node];
    int deg   = cnt[node];
    float sum = 0.0f;
    for (int c0 = 0; c0 < deg; c0 += 64) {
        int myi = c0 + lane;
        int sv  = (myi < deg) ? csr_src[start + myi] : 0;
        int m   = (deg - c0 < 64) ? (deg - c0) : 64;
        for (int j = 0; j < m; ++j) {
            int s = __shfl(sv, j);
            sum += h1[(s << 6) + lane];       // coalesced 256B row per edge
        }
    }
    float inv = 1.0f / fmaxf((float)deg, 1.0f);

    __shared__ float feat[4][128];
    feat[w][lane]      = h1[(node << 6) + lane];
    feat[w][64 + lane] = sum * inv;
    __syncthreads();

    float v = 0.0f;
    if (lane < 32) {
        float acc = b2[lane];
        #pragma unroll
        for (int k = 0; k < 128; ++k)
            acc += feat[w][k] * W2[k * 32 + lane];
        v = fmaxf(acc, 0.0f) * W3[lane];
    }
    for (int off = 32; off > 0; off >>= 1) v += __shfl_xor(v, off);
    if (lane == 0) out[node] = v + b3[0];
}

extern "C" void kernel_launch(void* const* d_in, const int* in_sizes, int n_in,
                              void* d_out, int out_size, void* d_ws, size_t ws_size,
                              hipStream_t stream) {
    const float* x   = (const float*)d_in[0];
    const int*   ei  = (const int*)d_in[1];
    const int*   src = ei;
    const int*   dst = ei + N_EDGES;
    const float* W1  = (const float*)d_in[2];
    const float* b1  = (const float*)d_in[3];
    const float* W2  = (const float*)d_in[4];
    const float* b2  = (const float*)d_in[5];
    const float* W3  = (const float*)d_in[6];
    const float* b3  = (const float*)d_in[7];
    float* out = (float*)d_out;

    // ws layout (all 256B-aligned): cnt[N] | row_start[N] | cursor[N] |
    //   chunksum[256] | chunkoff[256] | csr_src[E] | h1[N*64]   (~34 MB)
    char* ws = (char*)d_ws;
    auto align = [](size_t v) { return (v + 255) & ~(size_t)255; };
    size_t o = 0;
    int* cnt       = (int*)(ws + o); o = align(o + (size_t)N_NODES * 4);
    int* row_start = (int*)(ws + o); o = align(o + (size_t)N_NODES * 4);
    int* cursor    = (int*)(ws + o); o = align(o + (size_t)N_NODES * 4);
    int* chunksum  = (int*)(ws + o); o = align(o + 256 * 4);
    int* chunkoff  = (int*)(ws + o); o = align(o + 256 * 4);
    int* csr_src   = (int*)(ws + o); o = align(o + (size_t)N_EDGES * 4);
    float* h1      = (float*)(ws + o); o = align(o + (size_t)N_NODES * 64 * 4);

    hipMemsetAsync(cnt, 0, (size_t)N_NODES * sizeof(int), stream);

    hist_kernel<<<(N_EDGES + 255) / 256, 256, 0, stream>>>(dst, cnt);
    scan1_kernel<<<N_CHUNKS, 256, 0, stream>>>(cnt, chunksum);
    scan2_kernel<<<1, 256, 0, stream>>>(chunksum, chunkoff);
    scan3_kernel<<<N_CHUNKS, 256, 0, stream>>>(cnt, chunkoff, row_start, cursor);
    fill_kernel<<<(N_EDGES + 255) / 256, 256, 0, stream>>>(src, dst, cursor, csr_src);

    layer1_fused<<<N_NODES / 4, 256, 0, stream>>>(x, csr_src, row_start, cnt, W1, b1, h1);
    layer23_fused<<<N_NODES / 4, 256, 0, stream>>>(h1, csr_src, row_start, cnt, W2, b2, W3, b3, out);
}

// Round 3
// 507.496 us; speedup vs baseline: 2.1052x; 1.2482x over previous
//
#include <hip/hip_runtime.h>

#define N_NODES 100000
#define N_EDGES 1600000
#define IN_CH 50
#define SCAN_CHUNK 512
#define N_CHUNKS ((N_NODES + SCAN_CHUNK - 1) / SCAN_CHUNK)   // 196

// ---- 1. histogram of dst -> cnt (int) ----
__global__ void hist_kernel(const int* __restrict__ dst, int* __restrict__ cnt) {
    int e = blockIdx.x * blockDim.x + threadIdx.x;
    if (e < N_EDGES) atomicAdd(&cnt[dst[e]], 1);
}

// ---- 2a. per-chunk sums ----
__global__ __launch_bounds__(256) void scan1_kernel(const int* __restrict__ cnt,
                                                    int* __restrict__ chunksum) {
    __shared__ int s[256];
    int tid = threadIdx.x;
    int base = blockIdx.x * SCAN_CHUNK;
    int i0 = base + 2 * tid, i1 = i0 + 1;
    int a = (i0 < N_NODES) ? cnt[i0] : 0;
    int b = (i1 < N_NODES) ? cnt[i1] : 0;
    s[tid] = a + b;
    __syncthreads();
    for (int off = 128; off > 0; off >>= 1) {
        if (tid < off) s[tid] += s[tid + off];
        __syncthreads();
    }
    if (tid == 0) chunksum[blockIdx.x] = s[0];
}

// ---- 2b. exclusive scan of chunk sums (single block) ----
__global__ __launch_bounds__(256) void scan2_kernel(const int* __restrict__ chunksum,
                                                    int* __restrict__ chunkoff) {
    __shared__ int s[256];
    int tid = threadIdx.x;
    int v0 = (tid < N_CHUNKS) ? chunksum[tid] : 0;
    s[tid] = v0;
    __syncthreads();
    for (int off = 1; off < 256; off <<= 1) {
        int t = (tid >= off) ? s[tid - off] : 0;
        __syncthreads();
        s[tid] += t;
        __syncthreads();
    }
    if (tid < N_CHUNKS) chunkoff[tid] = s[tid] - v0;
}

// ---- 2c. per-chunk exclusive scan + offset -> row_start, cursor ----
__global__ __launch_bounds__(256) void scan3_kernel(const int* __restrict__ cnt,
                                                    const int* __restrict__ chunkoff,
                                                    int* __restrict__ row_start,
                                                    int* __restrict__ cursor) {
    __shared__ int s[256];
    int tid = threadIdx.x;
    int base = blockIdx.x * SCAN_CHUNK;
    int i0 = base + 2 * tid, i1 = i0 + 1;
    int a = (i0 < N_NODES) ? cnt[i0] : 0;
    int b = (i1 < N_NODES) ? cnt[i1] : 0;
    int pair = a + b;
    s[tid] = pair;
    __syncthreads();
    for (int off = 1; off < 256; off <<= 1) {
        int t = (tid >= off) ? s[tid - off] : 0;
        __syncthreads();
        s[tid] += t;
        __syncthreads();
    }
    int excl = s[tid] - pair;
    int o = chunkoff[blockIdx.x] + excl;
    if (i0 < N_NODES) { row_start[i0] = o;     cursor[i0] = o; }
    if (i1 < N_NODES) { row_start[i1] = o + a; cursor[i1] = o + a; }
}

// ---- 3. bucket placement ----
__global__ void fill_kernel(const int* __restrict__ src, const int* __restrict__ dst,
                            int* __restrict__ cursor, int* __restrict__ csr_src) {
    int e = blockIdx.x * blockDim.x + threadIdx.x;
    if (e < N_EDGES) {
        int pos = atomicAdd(&cursor[dst[e]], 1);
        csr_src[pos] = src[e];
    }
}

// ---- 3b. pad x [N,50] -> xp [N,64] (zeros in 50..63) ----
__global__ __launch_bounds__(256) void pad_kernel(const float* __restrict__ x,
                                                  float* __restrict__ xp) {
    int t = blockIdx.x * blockDim.x + threadIdx.x;   // N_NODES*64 threads
    int n = t >> 6, c = t & 63;
    xp[t] = (c < IN_CH) ? x[n * IN_CH + c] : 0.0f;
}

// gather-mean over csr row with 4 edges in flight: groups of 16 lanes each
// load a float4 (16B) of a different edge's stride-64 feature row.
// Returns float4 of channels (lane&15)*4 .. +3, replicated across groups.
__device__ __forceinline__ float4 gather_mean64(const float* __restrict__ feat64,
                                                const int* __restrict__ csr_src,
                                                int start, int deg, int lane) {
    int g  = lane >> 4;
    int c4 = (lane & 15) * 4;
    float ax = 0.f, ay = 0.f, az = 0.f, aw = 0.f;
    float bx = 0.f, by = 0.f, bz = 0.f, bw = 0.f;
    for (int c0 = 0; c0 < deg; c0 += 64) {
        int rem = deg - c0; if (rem > 64) rem = 64;
        int sv = (lane < rem) ? csr_src[start + c0 + lane] : 0;
        int cb = 0;
        for (; cb + 8 <= rem; cb += 8) {
            int s0 = __shfl(sv, cb + g);
            int s1 = __shfl(sv, cb + 4 + g);
            float4 v0 = *(const float4*)(feat64 + s0 * 64 + c4);
            float4 v1 = *(const float4*)(feat64 + s1 * 64 + c4);
            ax += v0.x; ay += v0.y; az += v0.z; aw += v0.w;
            bx += v1.x; by += v1.y; bz += v1.z; bw += v1.w;
        }
        for (; cb < rem; cb += 4) {
            int idx = cb + g;
            int s = __shfl(sv, idx < rem ? idx : 0);
            if (idx < rem) {
                float4 v = *(const float4*)(feat64 + s * 64 + c4);
                ax += v.x; ay += v.y; az += v.z; aw += v.w;
            }
        }
    }
    ax += bx; ay += by; az += bz; aw += bw;
    // merge the 4 lane-groups: all lanes end with full sums for their (lane&15)
    ax += __shfl_xor(ax, 16); ay += __shfl_xor(ay, 16);
    az += __shfl_xor(az, 16); aw += __shfl_xor(aw, 16);
    ax += __shfl_xor(ax, 32); ay += __shfl_xor(ay, 32);
    az += __shfl_xor(az, 32); aw += __shfl_xor(aw, 32);
    float inv = 1.0f / fmaxf((float)deg, 1.0f);
    return make_float4(ax * inv, ay * inv, az * inv, aw * inv);
}

// wave-local LDS fence: LDS ops of one wave complete in order; no block barrier.
#define WAVE_LDS_FENCE() __asm__ volatile("s_waitcnt lgkmcnt(0)" ::: "memory")

// ---- 4. layer 1 fused: gather-mean(xp) + concat + GEMM(100x64) + ReLU ----
__global__ __launch_bounds__(256) void layer1_fused(
    const float* __restrict__ x, const float* __restrict__ xp,
    const int* __restrict__ csr_src, const int* __restrict__ row_start,
    const int* __restrict__ cnt, const float* __restrict__ W1,
    const float* __restrict__ b1, float* __restrict__ h1) {
    int w    = threadIdx.x >> 6;
    int lane = threadIdx.x & 63;
    int node = blockIdx.x * 4 + w;            // N_NODES % 4 == 0

    float4 mean4 = gather_mean64(xp, csr_src, row_start[node], cnt[node], lane);

    __shared__ float selfF[4][64];
    __shared__ float meanF[4][64];
    if (lane < IN_CH) selfF[w][lane] = x[node * IN_CH + lane];
    if (lane < 16) *(float4*)&meanF[w][lane * 4] = mean4;
    WAVE_LDS_FENCE();

    float acc = b1[lane];
    #pragma unroll
    for (int k = 0; k < IN_CH; ++k)
        acc += selfF[w][k] * W1[k * 64 + lane];
    #pragma unroll
    for (int k = 0; k < IN_CH; ++k)
        acc += meanF[w][k] * W1[(IN_CH + k) * 64 + lane];
    h1[(node << 6) + lane] = fmaxf(acc, 0.0f);
}

// ---- 5. layers 2+3 fused: gather-mean(h1) + concat + GEMM(128x32) + ReLU + dot(W3) ----
__global__ __launch_bounds__(256) void layer23_fused(
    const float* __restrict__ h1, const int* __restrict__ csr_src,
    const int* __restrict__ row_start, const int* __restrict__ cnt,
    const float* __restrict__ W2, const float* __restrict__ b2,
    const float* __restrict__ W3, const float* __restrict__ b3,
    float* __restrict__ out) {
    int w    = threadIdx.x >> 6;
    int lane = threadIdx.x & 63;
    int node = blockIdx.x * 4 + w;

    float4 mean4 = gather_mean64(h1, csr_src, row_start[node], cnt[node], lane);

    __shared__ float selfF[4][64];
    __shared__ float meanF[4][64];
    selfF[w][lane] = h1[(node << 6) + lane];
    if (lane < 16) *(float4*)&meanF[w][lane * 4] = mean4;
    WAVE_LDS_FENCE();

    float v = 0.0f;
    if (lane < 32) {
        float acc = b2[lane];
        #pragma unroll
        for (int k = 0; k < 64; ++k)
            acc += selfF[w][k] * W2[k * 32 + lane];
        #pragma unroll
        for (int k = 0; k < 64; ++k)
            acc += meanF[w][k] * W2[(64 + k) * 32 + lane];
        v = fmaxf(acc, 0.0f) * W3[lane];
    }
    for (int off = 32; off > 0; off >>= 1) v += __shfl_xor(v, off);
    if (lane == 0) out[node] = v + b3[0];
}

extern "C" void kernel_launch(void* const* d_in, const int* in_sizes, int n_in,
                              void* d_out, int out_size, void* d_ws, size_t ws_size,
                              hipStream_t stream) {
    const float* x   = (const float*)d_in[0];
    const int*   ei  = (const int*)d_in[1];
    const int*   src = ei;
    const int*   dst = ei + N_EDGES;
    const float* W1  = (const float*)d_in[2];
    const float* b1  = (const float*)d_in[3];
    const float* W2  = (const float*)d_in[4];
    const float* b2  = (const float*)d_in[5];
    const float* W3  = (const float*)d_in[6];
    const float* b3  = (const float*)d_in[7];
    float* out = (float*)d_out;

    // ws layout: cnt[N] | row_start[N] | cursor[N] | chunksum | chunkoff |
    //            csr_src[E] | xp[N*64] | h1[N*64]   (~60 MB)
    char* ws = (char*)d_ws;
    auto align = [](size_t v) { return (v + 255) & ~(size_t)255; };
    size_t o = 0;
    int* cnt       = (int*)(ws + o); o = align(o + (size_t)N_NODES * 4);
    int* row_start = (int*)(ws + o); o = align(o + (size_t)N_NODES * 4);
    int* cursor    = (int*)(ws + o); o = align(o + (size_t)N_NODES * 4);
    int* chunksum  = (int*)(ws + o); o = align(o + 256 * 4);
    int* chunkoff  = (int*)(ws + o); o = align(o + 256 * 4);
    int* csr_src   = (int*)(ws + o); o = align(o + (size_t)N_EDGES * 4);
    float* xp      = (float*)(ws + o); o = align(o + (size_t)N_NODES * 64 * 4);
    float* h1      = (float*)(ws + o); o = align(o + (size_t)N_NODES * 64 * 4);

    hipMemsetAsync(cnt, 0, (size_t)N_NODES * sizeof(int), stream);

    hist_kernel<<<(N_EDGES + 255) / 256, 256, 0, stream>>>(dst, cnt);
    scan1_kernel<<<N_CHUNKS, 256, 0, stream>>>(cnt, chunksum);
    scan2_kernel<<<1, 256, 0, stream>>>(chunksum, chunkoff);
    scan3_kernel<<<N_CHUNKS, 256, 0, stream>>>(cnt, chunkoff, row_start, cursor);
    fill_kernel<<<(N_EDGES + 255) / 256, 256, 0, stream>>>(src, dst, cursor, csr_src);
    pad_kernel<<<(N_NODES * 64) / 256, 256, 0, stream>>>(x, xp);

    layer1_fused<<<N_NODES / 4, 256, 0, stream>>>(x, xp, csr_src, row_start, cnt, W1, b1, h1);
    layer23_fused<<<N_NODES / 4, 256, 0, stream>>>(h1, csr_src, row_start, cnt, W2, b2, W3, b3, out);
}

// Round 4
// 363.110 us; speedup vs baseline: 2.9423x; 1.3976x over previous
//
#include <hip/hip_runtime.h>

#define N_NODES 100000
#define N_EDGES 1600000
#define IN_CH 50
#define NPB 512                                   // nodes per bucket (dst >> 9)
#define NB ((N_NODES + NPB - 1) / NPB)            // 196 buckets
#define EPB 4096                                  // edges per block, binning passes
#define NBLK_A ((N_EDGES + EPB - 1) / EPB)        // 391 blocks

// ---- 1. coarse bucket histogram: LDS hist per block, 1 global atomic/bucket/block ----
__global__ __launch_bounds__(256) void bucket_count(const int* __restrict__ dst,
                                                    int* __restrict__ bucket_cnt) {
    __shared__ int bc[NB];
    int t = threadIdx.x;
    if (t < NB) bc[t] = 0;
    __syncthreads();
    int e0 = blockIdx.x * EPB;
    int e1 = min(e0 + EPB, N_EDGES);
    for (int i = e0 + t; i < e1; i += 256)
        atomicAdd(&bc[dst[i] >> 9], 1);
    __syncthreads();
    if (t < NB) { int v = bc[t]; if (v) atomicAdd(&bucket_cnt[t], v); }
}

// ---- 2. exclusive scan of bucket sizes -> base, cursor ----
__global__ __launch_bounds__(256) void bucket_scan(const int* __restrict__ bucket_cnt,
                                                   int* __restrict__ bucket_base,
                                                   int* __restrict__ bucket_cursor) {
    __shared__ int s[256];
    int t = threadIdx.x;
    int v = (t < NB) ? bucket_cnt[t] : 0;
    s[t] = v;
    __syncthreads();
    for (int off = 1; off < 256; off <<= 1) {
        int tmp = (t >= off) ? s[t - off] : 0;
        __syncthreads();
        s[t] += tmp;
        __syncthreads();
    }
    if (t < NB) { int base = s[t] - v; bucket_base[t] = base; bucket_cursor[t] = base; }
}

// ---- 3. bin edges into coarse buckets as packed (dst<<32 | src) ----
__global__ __launch_bounds__(256) void bucket_bin(const int* __restrict__ src,
                                                  const int* __restrict__ dst,
                                                  int* __restrict__ bucket_cursor,
                                                  unsigned long long* __restrict__ binned) {
    __shared__ int bc[NB];
    __shared__ int boff[NB];
    int t = threadIdx.x;
    if (t < NB) bc[t] = 0;
    __syncthreads();
    int e0 = blockIdx.x * EPB;
    int e1 = min(e0 + EPB, N_EDGES);
    for (int i = e0 + t; i < e1; i += 256)
        atomicAdd(&bc[dst[i] >> 9], 1);
    __syncthreads();
    if (t < NB) {
        int v = bc[t];
        boff[t] = v ? atomicAdd(&bucket_cursor[t], v) : 0;
        bc[t] = 0;                                 // reuse as local cursor
    }
    __syncthreads();
    for (int i = e0 + t; i < e1; i += 256) {
        int d = dst[i];
        int b = d >> 9;
        int k = atomicAdd(&bc[b], 1);
        binned[boff[b] + k] =
            ((unsigned long long)(unsigned)d << 32) | (unsigned)src[i];
    }
}

// ---- 4. per-bucket fine sort: LDS hist + scan -> cnt, row_start, csr_src ----
__global__ __launch_bounds__(256) void bucket_fine(
    const unsigned long long* __restrict__ binned,
    const int* __restrict__ bucket_base, const int* __restrict__ bucket_cnt,
    int* __restrict__ cnt, int* __restrict__ row_start, int* __restrict__ csr_src) {
    __shared__ int lcnt[NPB];
    __shared__ int lofs[NPB];
    __shared__ int sc[256];
    int t = threadIdx.x;
    int b = blockIdx.x;
    int nbase = b * NPB;
    int ebase = bucket_base[b];
    int ecnt  = bucket_cnt[b];
    lcnt[t] = 0; lcnt[t + 256] = 0;
    __syncthreads();
    for (int i = t; i < ecnt; i += 256) {
        int d = (int)(binned[ebase + i] >> 32) - nbase;
        atomicAdd(&lcnt[d], 1);
    }
    __syncthreads();
    int v0 = lcnt[2 * t], v1 = lcnt[2 * t + 1];
    int pair = v0 + v1;
    sc[t] = pair;
    __syncthreads();
    for (int off = 1; off < 256; off <<= 1) {
        int tmp = (t >= off) ? sc[t - off] : 0;
        __syncthreads();
        sc[t] += tmp;
        __syncthreads();
    }
    int excl = sc[t] - pair;
    lofs[2 * t] = excl;
    lofs[2 * t + 1] = excl + v0;
    __syncthreads();
    {
        int n0 = nbase + t;
        if (n0 < N_NODES) { cnt[n0] = lcnt[t]; row_start[n0] = ebase + lofs[t]; }
        int n1 = nbase + t + 256;
        if (n1 < N_NODES) { cnt[n1] = lcnt[t + 256]; row_start[n1] = ebase + lofs[t + 256]; }
    }
    __syncthreads();
    for (int i = t; i < ecnt; i += 256) {
        unsigned long long p = binned[ebase + i];
        int d = (int)(p >> 32) - nbase;
        int k = atomicAdd(&lofs[d], 1);
        csr_src[ebase + k] = (int)(p & 0xffffffffULL);   // 32KB window, one XCD
    }
}

// ---- 5. pad x [N,50] -> xp [N,64] ----
__global__ __launch_bounds__(256) void pad_kernel(const float* __restrict__ x,
                                                  float* __restrict__ xp) {
    int t = blockIdx.x * blockDim.x + threadIdx.x;
    int n = t >> 6, c = t & 63;
    xp[t] = (c < IN_CH) ? x[n * IN_CH + c] : 0.0f;
}

// gather-mean: 4 lane-groups of 16 each load a float4 of a different edge's row
__device__ __forceinline__ float4 gather_mean64(const float* __restrict__ feat64,
                                                const int* __restrict__ csr_src,
                                                int start, int deg, int lane) {
    int g  = lane >> 4;
    int c4 = (lane & 15) * 4;
    float ax = 0.f, ay = 0.f, az = 0.f, aw = 0.f;
    float bx = 0.f, by = 0.f, bz = 0.f, bw = 0.f;
    for (int c0 = 0; c0 < deg; c0 += 64) {
        int rem = deg - c0; if (rem > 64) rem = 64;
        int sv = (lane < rem) ? csr_src[start + c0 + lane] : 0;
        int cb = 0;
        for (; cb + 8 <= rem; cb += 8) {
            int s0 = __shfl(sv, cb + g);
            int s1 = __shfl(sv, cb + 4 + g);
            float4 v0 = *(const float4*)(feat64 + s0 * 64 + c4);
            float4 v1 = *(const float4*)(feat64 + s1 * 64 + c4);
            ax += v0.x; ay += v0.y; az += v0.z; aw += v0.w;
            bx += v1.x; by += v1.y; bz += v1.z; bw += v1.w;
        }
        for (; cb < rem; cb += 4) {
            int idx = cb + g;
            int s = __shfl(sv, idx < rem ? idx : 0);
            if (idx < rem) {
                float4 v = *(const float4*)(feat64 + s * 64 + c4);
                ax += v.x; ay += v.y; az += v.z; aw += v.w;
            }
        }
    }
    ax += bx; ay += by; az += bz; aw += bw;
    ax += __shfl_xor(ax, 16); ay += __shfl_xor(ay, 16);
    az += __shfl_xor(az, 16); aw += __shfl_xor(aw, 16);
    ax += __shfl_xor(ax, 32); ay += __shfl_xor(ay, 32);
    az += __shfl_xor(az, 32); aw += __shfl_xor(aw, 32);
    float inv = 1.0f / fmaxf((float)deg, 1.0f);
    return make_float4(ax * inv, ay * inv, az * inv, aw * inv);
}

#define WAVE_LDS_FENCE() __asm__ volatile("s_waitcnt lgkmcnt(0)" ::: "memory")

// ---- 6. layer 1 fused ----
__global__ __launch_bounds__(256) void layer1_fused(
    const float* __restrict__ x, const float* __restrict__ xp,
    const int* __restrict__ csr_src, const int* __restrict__ row_start,
    const int* __restrict__ cnt, const float* __restrict__ W1,
    const float* __restrict__ b1, float* __restrict__ h1) {
    int w    = threadIdx.x >> 6;
    int lane = threadIdx.x & 63;
    int node = blockIdx.x * 4 + w;

    float4 mean4 = gather_mean64(xp, csr_src, row_start[node], cnt[node], lane);

    __shared__ float selfF[4][64];
    __shared__ float meanF[4][64];
    if (lane < IN_CH) selfF[w][lane] = x[node * IN_CH + lane];
    if (lane < 16) *(float4*)&meanF[w][lane * 4] = mean4;
    WAVE_LDS_FENCE();

    float acc = b1[lane];
    #pragma unroll
    for (int k = 0; k < IN_CH; ++k)
        acc += selfF[w][k] * W1[k * 64 + lane];
    #pragma unroll
    for (int k = 0; k < IN_CH; ++k)
        acc += meanF[w][k] * W1[(IN_CH + k) * 64 + lane];
    h1[(node << 6) + lane] = fmaxf(acc, 0.0f);
}

// ---- 7. layers 2+3 fused ----
__global__ __launch_bounds__(256) void layer23_fused(
    const float* __restrict__ h1, const int* __restrict__ csr_src,
    const int* __restrict__ row_start, const int* __restrict__ cnt,
    const float* __restrict__ W2, const float* __restrict__ b2,
    const float* __restrict__ W3, const float* __restrict__ b3,
    float* __restrict__ out) {
    int w    = threadIdx.x >> 6;
    int lane = threadIdx.x & 63;
    int node = blockIdx.x * 4 + w;

    float4 mean4 = gather_mean64(h1, csr_src, row_start[node], cnt[node], lane);

    __shared__ float selfF[4][64];
    __shared__ float meanF[4][64];
    selfF[w][lane] = h1[(node << 6) + lane];
    if (lane < 16) *(float4*)&meanF[w][lane * 4] = mean4;
    WAVE_LDS_FENCE();

    float v = 0.0f;
    if (lane < 32) {
        float acc = b2[lane];
        #pragma unroll
        for (int k = 0; k < 64; ++k)
            acc += selfF[w][k] * W2[k * 32 + lane];
        #pragma unroll
        for (int k = 0; k < 64; ++k)
            acc += meanF[w][k] * W2[(64 + k) * 32 + lane];
        v = fmaxf(acc, 0.0f) * W3[lane];
    }
    for (int off = 32; off > 0; off >>= 1) v += __shfl_xor(v, off);
    if (lane == 0) out[node] = v + b3[0];
}

extern "C" void kernel_launch(void* const* d_in, const int* in_sizes, int n_in,
                              void* d_out, int out_size, void* d_ws, size_t ws_size,
                              hipStream_t stream) {
    const float* x   = (const float*)d_in[0];
    const int*   ei  = (const int*)d_in[1];
    const int*   src = ei;
    const int*   dst = ei + N_EDGES;
    const float* W1  = (const float*)d_in[2];
    const float* b1  = (const float*)d_in[3];
    const float* W2  = (const float*)d_in[4];
    const float* b2  = (const float*)d_in[5];
    const float* W3  = (const float*)d_in[6];
    const float* b3  = (const float*)d_in[7];
    float* out = (float*)d_out;

    // ws layout (~58 MB): bucket arrays | cnt | row_start | csr_src |
    //   [binned u64[E] ALIASED with xp f32[N*64] -- binned dead before pad] | h1
    char* ws = (char*)d_ws;
    auto align = [](size_t v) { return (v + 255) & ~(size_t)255; };
    size_t o = 0;
    int* bucket_cnt    = (int*)(ws + o); o = align(o + 256 * 4);
    int* bucket_base   = (int*)(ws + o); o = align(o + 256 * 4);
    int* bucket_cursor = (int*)(ws + o); o = align(o + 256 * 4);
    int* cnt       = (int*)(ws + o); o = align(o + (size_t)N_NODES * 4);
    int* row_start = (int*)(ws + o); o = align(o + (size_t)N_NODES * 4);
    int* csr_src   = (int*)(ws + o); o = align(o + (size_t)N_EDGES * 4);
    unsigned long long* binned = (unsigned long long*)(ws + o);   // 8*E = 12.8 MB
    float* xp = (float*)(ws + o);                                 // 25.6 MB (alias)
    o = align(o + (size_t)N_NODES * 64 * 4);
    float* h1 = (float*)(ws + o); o = align(o + (size_t)N_NODES * 64 * 4);

    hipMemsetAsync(bucket_cnt, 0, 256 * sizeof(int), stream);

    bucket_count<<<NBLK_A, 256, 0, stream>>>(dst, bucket_cnt);
    bucket_scan<<<1, 256, 0, stream>>>(bucket_cnt, bucket_base, bucket_cursor);
    bucket_bin<<<NBLK_A, 256, 0, stream>>>(src, dst, bucket_cursor, binned);
    bucket_fine<<<NB, 256, 0, stream>>>(binned, bucket_base, bucket_cnt,
                                        cnt, row_start, csr_src);
    pad_kernel<<<(N_NODES * 64) / 256, 256, 0, stream>>>(x, xp);

    layer1_fused<<<N_NODES / 4, 256, 0, stream>>>(x, xp, csr_src, row_start, cnt, W1, b1, h1);
    layer23_fused<<<N_NODES / 4, 256, 0, stream>>>(h1, csr_src, row_start, cnt, W2, b2, W3, b3, out);
}

// Round 5
// 347.688 us; speedup vs baseline: 3.0728x; 1.0444x over previous
//
#include <hip/hip_runtime.h>
#include <hip/hip_bf16.h>

#define N_NODES 100000
#define N_EDGES 1600000
#define IN_CH 50
#define NPB 512                                   // nodes per bucket (dst >> 9)
#define NB ((N_NODES + NPB - 1) / NPB)            // 196 buckets
#define EPB 4096                                  // edges per block, binning passes
#define NBLK_A ((N_EDGES + EPB - 1) / EPB)        // 391 blocks

// ---- 1. coarse bucket histogram ----
__global__ __launch_bounds__(256) void bucket_count(const int* __restrict__ dst,
                                                    int* __restrict__ bucket_cnt) {
    __shared__ int bc[NB];
    int t = threadIdx.x;
    if (t < NB) bc[t] = 0;
    __syncthreads();
    int e0 = blockIdx.x * EPB;
    int e1 = min(e0 + EPB, N_EDGES);
    for (int i = e0 + t; i < e1; i += 256)
        atomicAdd(&bc[dst[i] >> 9], 1);
    __syncthreads();
    if (t < NB) { int v = bc[t]; if (v) atomicAdd(&bucket_cnt[t], v); }
}

// ---- 2. exclusive scan of bucket sizes ----
__global__ __launch_bounds__(256) void bucket_scan(const int* __restrict__ bucket_cnt,
                                                   int* __restrict__ bucket_base,
                                                   int* __restrict__ bucket_cursor) {
    __shared__ int s[256];
    int t = threadIdx.x;
    int v = (t < NB) ? bucket_cnt[t] : 0;
    s[t] = v;
    __syncthreads();
    for (int off = 1; off < 256; off <<= 1) {
        int tmp = (t >= off) ? s[t - off] : 0;
        __syncthreads();
        s[t] += tmp;
        __syncthreads();
    }
    if (t < NB) { int base = s[t] - v; bucket_base[t] = base; bucket_cursor[t] = base; }
}

// ---- 3. bin edges into coarse buckets as packed (dst<<32 | src) ----
__global__ __launch_bounds__(256) void bucket_bin(const int* __restrict__ src,
                                                  const int* __restrict__ dst,
                                                  int* __restrict__ bucket_cursor,
                                                  unsigned long long* __restrict__ binned) {
    __shared__ int bc[NB];
    __shared__ int boff[NB];
    int t = threadIdx.x;
    if (t < NB) bc[t] = 0;
    __syncthreads();
    int e0 = blockIdx.x * EPB;
    int e1 = min(e0 + EPB, N_EDGES);
    for (int i = e0 + t; i < e1; i += 256)
        atomicAdd(&bc[dst[i] >> 9], 1);
    __syncthreads();
    if (t < NB) {
        int v = bc[t];
        boff[t] = v ? atomicAdd(&bucket_cursor[t], v) : 0;
        bc[t] = 0;
    }
    __syncthreads();
    for (int i = e0 + t; i < e1; i += 256) {
        int d = dst[i];
        int b = d >> 9;
        int k = atomicAdd(&bc[b], 1);
        binned[boff[b] + k] =
            ((unsigned long long)(unsigned)d << 32) | (unsigned)src[i];
    }
}

// ---- 4. per-bucket fine sort ----
__global__ __launch_bounds__(256) void bucket_fine(
    const unsigned long long* __restrict__ binned,
    const int* __restrict__ bucket_base, const int* __restrict__ bucket_cnt,
    int* __restrict__ cnt, int* __restrict__ row_start, int* __restrict__ csr_src) {
    __shared__ int lcnt[NPB];
    __shared__ int lofs[NPB];
    __shared__ int sc[256];
    int t = threadIdx.x;
    int b = blockIdx.x;
    int nbase = b * NPB;
    int ebase = bucket_base[b];
    int ecnt  = bucket_cnt[b];
    lcnt[t] = 0; lcnt[t + 256] = 0;
    __syncthreads();
    for (int i = t; i < ecnt; i += 256) {
        int d = (int)(binned[ebase + i] >> 32) - nbase;
        atomicAdd(&lcnt[d], 1);
    }
    __syncthreads();
    int v0 = lcnt[2 * t], v1 = lcnt[2 * t + 1];
    int pair = v0 + v1;
    sc[t] = pair;
    __syncthreads();
    for (int off = 1; off < 256; off <<= 1) {
        int tmp = (t >= off) ? sc[t - off] : 0;
        __syncthreads();
        sc[t] += tmp;
        __syncthreads();
    }
    int excl = sc[t] - pair;
    lofs[2 * t] = excl;
    lofs[2 * t + 1] = excl + v0;
    __syncthreads();
    {
        int n0 = nbase + t;
        if (n0 < N_NODES) { cnt[n0] = lcnt[t]; row_start[n0] = ebase + lofs[t]; }
        int n1 = nbase + t + 256;
        if (n1 < N_NODES) { cnt[n1] = lcnt[t + 256]; row_start[n1] = ebase + lofs[t + 256]; }
    }
    __syncthreads();
    for (int i = t; i < ecnt; i += 256) {
        unsigned long long p = binned[ebase + i];
        int d = (int)(p >> 32) - nbase;
        int k = atomicAdd(&lofs[d], 1);
        csr_src[ebase + k] = (int)(p & 0xffffffffULL);
    }
}

// ---- 5. pad+quantize x [N,50] fp32 -> xb [N,64] bf16 ----
__global__ __launch_bounds__(256) void pad_bf16_kernel(const float* __restrict__ x,
                                                       __hip_bfloat16* __restrict__ xb) {
    int t = blockIdx.x * blockDim.x + threadIdx.x;
    int n = t >> 6, c = t & 63;
    float v = (c < IN_CH) ? x[n * IN_CH + c] : 0.0f;
    xb[t] = __float2bfloat16(v);
}

// gather-mean over bf16 rows (64 ch = 128B): 8 lane-groups of 8, each group one
// edge, each lane a uint4 (8 bf16). 16 edges in flight per unrolled iteration.
// Result: all lanes hold full sums; channels for lane l&7: 8*(l&7)+0..7 in acc0..7.
#define UNPACK_ADD(vv)                                                        \
    {                                                                         \
        acc0 += __uint_as_float((vv).x << 16);                                \
        acc1 += __uint_as_float((vv).x & 0xffff0000u);                        \
        acc2 += __uint_as_float((vv).y << 16);                                \
        acc3 += __uint_as_float((vv).y & 0xffff0000u);                        \
        acc4 += __uint_as_float((vv).z << 16);                                \
        acc5 += __uint_as_float((vv).z & 0xffff0000u);                        \
        acc6 += __uint_as_float((vv).w << 16);                                \
        acc7 += __uint_as_float((vv).w & 0xffff0000u);                        \
    }

__device__ __forceinline__ void gather_mean_bf16(
    const __hip_bfloat16* __restrict__ featb, const int* __restrict__ csr_src,
    int start, int deg, int lane, float* __restrict__ lds_row /* 64 floats */) {
    int g  = lane >> 3;                 // edge-in-flight id 0..7
    int cw = (lane & 7) * 8;            // ushort offset within row (16B chunk)
    float acc0 = 0.f, acc1 = 0.f, acc2 = 0.f, acc3 = 0.f;
    float acc4 = 0.f, acc5 = 0.f, acc6 = 0.f, acc7 = 0.f;
    for (int c0 = 0; c0 < deg; c0 += 64) {
        int rem = deg - c0; if (rem > 64) rem = 64;
        int sv = (lane < rem) ? csr_src[start + c0 + lane] : 0;
        int cb = 0;
        for (; cb + 16 <= rem; cb += 16) {
            int s0 = __shfl(sv, cb + g);
            int s1 = __shfl(sv, cb + 8 + g);
            uint4 v0 = *(const uint4*)((const unsigned short*)featb + s0 * 64 + cw);
            uint4 v1 = *(const uint4*)((const unsigned short*)featb + s1 * 64 + cw);
            UNPACK_ADD(v0);
            UNPACK_ADD(v1);
        }
        for (; cb < rem; cb += 8) {
            int idx = cb + g;
            int s = __shfl(sv, idx < rem ? idx : 0);
            if (idx < rem) {
                uint4 v = *(const uint4*)((const unsigned short*)featb + s * 64 + cw);
                UNPACK_ADD(v);
            }
        }
    }
    // merge the 8 lane-groups
    for (int off = 8; off <= 32; off <<= 1) {
        acc0 += __shfl_xor(acc0, off); acc1 += __shfl_xor(acc1, off);
        acc2 += __shfl_xor(acc2, off); acc3 += __shfl_xor(acc3, off);
        acc4 += __shfl_xor(acc4, off); acc5 += __shfl_xor(acc5, off);
        acc6 += __shfl_xor(acc6, off); acc7 += __shfl_xor(acc7, off);
    }
    float inv = 1.0f / fmaxf((float)deg, 1.0f);
    if (lane < 8) {
        *(float4*)&lds_row[lane * 8]     = make_float4(acc0 * inv, acc1 * inv, acc2 * inv, acc3 * inv);
        *(float4*)&lds_row[lane * 8 + 4] = make_float4(acc4 * inv, acc5 * inv, acc6 * inv, acc7 * inv);
    }
}

// wave-local LDS fence: LDS ops of one wave complete in order; no block barrier.
#define WAVE_LDS_FENCE() __asm__ volatile("s_waitcnt lgkmcnt(0)" ::: "memory")

// ---- 6. layer 1 fused: gather-mean(xb bf16) + fp32 self + GEMM(100x64) + ReLU ----
__global__ __launch_bounds__(256) void layer1_fused(
    const float* __restrict__ x, const __hip_bfloat16* __restrict__ xb,
    const int* __restrict__ csr_src, const int* __restrict__ row_start,
    const int* __restrict__ cnt, const float* __restrict__ W1,
    const float* __restrict__ b1, float* __restrict__ h1,
    __hip_bfloat16* __restrict__ h1b) {
    int w    = threadIdx.x >> 6;
    int lane = threadIdx.x & 63;
    int node = blockIdx.x * 4 + w;            // N_NODES % 4 == 0

    __shared__ __align__(16) float selfF[4][64];
    __shared__ __align__(16) float meanF[4][64];

    gather_mean_bf16(xb, csr_src, row_start[node], cnt[node], lane, meanF[w]);
    if (lane < IN_CH) selfF[w][lane] = x[node * IN_CH + lane];
    WAVE_LDS_FENCE();

    float acc = b1[lane];
    #pragma unroll
    for (int k = 0; k < IN_CH; ++k)
        acc += selfF[w][k] * W1[k * 64 + lane];
    #pragma unroll
    for (int k = 0; k < IN_CH; ++k)
        acc += meanF[w][k] * W1[(IN_CH + k) * 64 + lane];
    float r = fmaxf(acc, 0.0f);
    h1 [(node << 6) + lane] = r;
    h1b[(node << 6) + lane] = __float2bfloat16(r);
}

// ---- 7. layers 2+3 fused: gather-mean(h1b bf16) + fp32 self + GEMM(128x32) + dot(W3) ----
__global__ __launch_bounds__(256) void layer23_fused(
    const float* __restrict__ h1, const __hip_bfloat16* __restrict__ h1b,
    const int* __restrict__ csr_src, const int* __restrict__ row_start,
    const int* __restrict__ cnt, const float* __restrict__ W2,
    const float* __restrict__ b2, const float* __restrict__ W3,
    const float* __restrict__ b3, float* __restrict__ out) {
    int w    = threadIdx.x >> 6;
    int lane = threadIdx.x & 63;
    int node = blockIdx.x * 4 + w;

    __shared__ __align__(16) float selfF[4][64];
    __shared__ __align__(16) float meanF[4][64];

    gather_mean_bf16(h1b, csr_src, row_start[node], cnt[node], lane, meanF[w]);
    selfF[w][lane] = h1[(node << 6) + lane];
    WAVE_LDS_FENCE();

    float v = 0.0f;
    if (lane < 32) {
        float acc = b2[lane];
        #pragma unroll
        for (int k = 0; k < 64; ++k)
            acc += selfF[w][k] * W2[k * 32 + lane];
        #pragma unroll
        for (int k = 0; k < 64; ++k)
            acc += meanF[w][k] * W2[(64 + k) * 32 + lane];
        v = fmaxf(acc, 0.0f) * W3[lane];
    }
    for (int off = 32; off > 0; off >>= 1) v += __shfl_xor(v, off);
    if (lane == 0) out[node] = v + b3[0];
}

extern "C" void kernel_launch(void* const* d_in, const int* in_sizes, int n_in,
                              void* d_out, int out_size, void* d_ws, size_t ws_size,
                              hipStream_t stream) {
    const float* x   = (const float*)d_in[0];
    const int*   ei  = (const int*)d_in[1];
    const int*   src = ei;
    const int*   dst = ei + N_EDGES;
    const float* W1  = (const float*)d_in[2];
    const float* b1  = (const float*)d_in[3];
    const float* W2  = (const float*)d_in[4];
    const float* b2  = (const float*)d_in[5];
    const float* W3  = (const float*)d_in[6];
    const float* b3  = (const float*)d_in[7];
    float* out = (float*)d_out;

    // ws (~58 MB): buckets | cnt | row_start | csr_src |
    //   [binned u64[E] 12.8MB ALIASED with xb bf16[N*64] 12.8MB] | h1 f32 | h1b bf16
    char* ws = (char*)d_ws;
    auto align = [](size_t v) { return (v + 255) & ~(size_t)255; };
    size_t o = 0;
    int* bucket_cnt    = (int*)(ws + o); o = align(o + 256 * 4);
    int* bucket_base   = (int*)(ws + o); o = align(o + 256 * 4);
    int* bucket_cursor = (int*)(ws + o); o = align(o + 256 * 4);
    int* cnt       = (int*)(ws + o); o = align(o + (size_t)N_NODES * 4);
    int* row_start = (int*)(ws + o); o = align(o + (size_t)N_NODES * 4);
    int* csr_src   = (int*)(ws + o); o = align(o + (size_t)N_EDGES * 4);
    unsigned long long* binned = (unsigned long long*)(ws + o);      // 12.8 MB
    __hip_bfloat16* xb = (__hip_bfloat16*)(ws + o);                  // alias (binned dead first)
    o = align(o + (size_t)N_EDGES * 8);
    float* h1 = (float*)(ws + o); o = align(o + (size_t)N_NODES * 64 * 4);
    __hip_bfloat16* h1b = (__hip_bfloat16*)(ws + o); o = align(o + (size_t)N_NODES * 64 * 2);

    hipMemsetAsync(bucket_cnt, 0, 256 * sizeof(int), stream);

    bucket_count<<<NBLK_A, 256, 0, stream>>>(dst, bucket_cnt);
    bucket_scan<<<1, 256, 0, stream>>>(bucket_cnt, bucket_base, bucket_cursor);
    bucket_bin<<<NBLK_A, 256, 0, stream>>>(src, dst, bucket_cursor, binned);
    bucket_fine<<<NB, 256, 0, stream>>>(binned, bucket_base, bucket_cnt,
                                        cnt, row_start, csr_src);
    pad_bf16_kernel<<<(N_NODES * 64) / 256, 256, 0, stream>>>(x, xb);

    layer1_fused<<<N_NODES / 4, 256, 0, stream>>>(x, xb, csr_src, row_start, cnt,
                                                  W1, b1, h1, h1b);
    layer23_fused<<<N_NODES / 4, 256, 0, stream>>>(h1, h1b, csr_src, row_start, cnt,
                                                   W2, b2, W3, b3, out);
}